// Round 15
// baseline (290.909 us; speedup 1.0000x reference)
//
#include <hip/hip_runtime.h>
#include <hip/hip_bf16.h>

#define BATCH 32
#define T 1024
#define G 2                        // pipeline stages (blocks) per batch
#define NTH 512                    // threads per stage block, 1 col/thread
#define WVS 8                      // 8 waves = 2 waves/SIMD
#define KS 8                       // steps per barrier window = rows per chunk
#define DOW 71                     // inter-wave offset (63 + KS)
#define SKEW (DOW * (WVS - 1) + 63)   // 560
#define TOT (SKEW + T)             // 1584
#define NB (TOT / KS)              // 198 windows
#define NCHUNK (T / KS)            // 128 chunks per interface
#define MARGIN 8                   // startup lead (chunks)
#define SENT_U 0xAAAAAAAAu
#define BIGF 1e10f
#define K2f 14.426950408889634f    // 1/(gamma*ln2), gamma=0.1
#define GLN2f 0.0693147180559945f  // gamma*ln2
#define KQTSE_ 0.1f

// workspace layout
#define EDGE_BYTES (BATCH * T * 4) // 131072: one interface per batch (G=2)
#define SDTW_OFF EDGE_BYTES
#define WS_NEEDED (size_t)(SDTW_OFF + BATCH * 4)

typedef float f32x4 __attribute__((ext_vector_type(4)));

// Raw v_exp_f32 (R14-proven: exp2f's __ocml fixup was ~40% of cell issue).
__device__ __forceinline__ float fexp2(float x) {
    float r;
    asm("v_exp_f32 %0, %1" : "=v"(r) : "v"(x));
    return r;
}

// Exact softmin_gamma(a,b,c): m - g*ln(1 + 2^{K(m-md)} + 2^{K(m-M)}) (one exp folded).
__device__ __forceinline__ float softmin3(float a, float b, float c) {
    float m  = fminf(fminf(a, b), c);             // v_min3_f32
    float M  = fmaxf(fmaxf(a, b), c);             // v_max3_f32
    float md = __builtin_amdgcn_fmed3f(a, b, c);  // v_med3_f32
    float mk = m * K2f;
    float e1 = fexp2(fmaf(-K2f, md, mk));
    float e2 = fexp2(fmaf(-K2f, M, mk));
    return fmaf(-GLN2f, __log2f(1.0f + e1 + e2), m);
}

// lane i gets src[lane i-1]; lane 0 keeps `old` (bound_ctrl=false fuses the select).
__device__ __forceinline__ float lane_shr1(float old, float src) {
    return __int_as_float(__builtin_amdgcn_update_dpp(
        __float_as_int(old), __float_as_int(src), 0x138, 0xF, 0xF, false));
}

// Raw block barrier draining ONLY lgkmcnt (LDS ring ordering). Global
// stores/loads stay in flight across it — removes the ~900 cy vmcnt(0)
// drain __syncthreads() would impose on the producer's sc0sc1 stores
// (HK T3/T4 pattern: counted vmem across raw s_barrier, m201-proven).
__device__ __forceinline__ void block_sync_lds() {
    __builtin_amdgcn_sched_barrier(0);
    asm volatile("s_waitcnt lgkmcnt(0)" ::: "memory");
    __builtin_amdgcn_s_barrier();
    __builtin_amdgcn_sched_barrier(0);
}

// ---- device-coherent transport (R9/R11/R13-proven): sc0 sc1 both ways ----
__device__ __forceinline__ void issue_load8(const float* base, f32x4& a, f32x4& b) {
    asm volatile("global_load_dwordx4 %0, %2, off sc0 sc1\n\t"
                 "global_load_dwordx4 %1, %2, off offset:16 sc0 sc1"
                 : "=&v"(a), "=&v"(b) : "v"(base));
}
__device__ __forceinline__ void await_load8(f32x4& a, f32x4& b) {
    asm volatile("s_waitcnt vmcnt(0)" : "+v"(a), "+v"(b) :: "memory");
    __builtin_amdgcn_sched_barrier(0);
}
__device__ __forceinline__ bool has_sent(const f32x4& a, const f32x4& b) {
    return (__float_as_uint(a.x) == SENT_U) | (__float_as_uint(a.y) == SENT_U) |
           (__float_as_uint(a.z) == SENT_U) | (__float_as_uint(a.w) == SENT_U) |
           (__float_as_uint(b.x) == SENT_U) | (__float_as_uint(b.y) == SENT_U) |
           (__float_as_uint(b.z) == SENT_U) | (__float_as_uint(b.w) == SENT_U);
}
__device__ __forceinline__ void spin_load8(const float* base, f32x4& a, f32x4& b) {
    issue_load8(base, a, b);
    await_load8(a, b);
    while (has_sent(a, b)) {
        __builtin_amdgcn_s_sleep(8);
        issue_load8(base, a, b);
        await_load8(a, b);
    }
}
__device__ __forceinline__ void store_edge8(float* base, const f32x4& a, const f32x4& b) {
    asm volatile("global_store_dwordx4 %0, %1, off sc0 sc1\n\t"
                 "global_store_dwordx4 %0, %2, off offset:16 sc0 sc1"
                 :: "v"(base), "v"(a), "v"(b) : "memory");
}

// G=2 pipelined wave-systolic soft-DTW: R13 structure + R14 cell + raw barrier.
__global__ __launch_bounds__(NTH) void sdtw_pipe(const float* __restrict__ pred,
                                                 const float* __restrict__ targ,
                                                 float* __restrict__ edges,
                                                 float* __restrict__ sdtw_out) {
    __shared__ float p[T];
    __shared__ float ring[WVS - 1][T];   // 28 KB

    const int blk = blockIdx.x;
    const int b = blk & (BATCH - 1);
    const int g = blk >> 5;
    const int tid = threadIdx.x;
    const int wv = tid >> 6;
    const int ln = tid & 63;
    const int myoff = DOW * wv + ln;

    ((float2*)p)[tid] = ((const float2*)(pred + b * T))[tid];
    const float tc = targ[b * T + g * (T / G) + tid];
    const float zcc = (g == 0 && tid == 0) ? 0.0f : BIGF;   // R[0][0]=0 else BIG

    const float* eb = edges + b * T;     // single interface per batch (G=2)
    const bool consumer = (g == 1) && (tid == 0);
    const bool producing = (g == 0) && (tid == NTH - 1);

    float top = BIGF, corner = BIGF, rc = BIGF, result = 0.0f;
    float rlg[KS];
#pragma unroll
    for (int i = 0; i < KS; ++i) rlg[i] = BIGF;

    __syncthreads();   // one full barrier after staging loads (outside the loop)

    if (consumer) {
        f32x4 a, b4;
        spin_load8(eb + (MARGIN - 1) * KS, a, b4);   // establish startup lead
        spin_load8(eb, a, b4);                       // chunk 0
        rlg[0] = a.x; rlg[1] = a.y; rlg[2] = a.z; rlg[3] = a.w;
        rlg[4] = b4.x; rlg[5] = b4.y; rlg[6] = b4.z; rlg[7] = b4.w;
    }

    for (int sb = 0; sb < NB; ++sb) {
        const int ics = sb * KS - myoff;

        // lane-0 left-edge batch (off the dependence chain)
        float rl[KS];
#pragma unroll
        for (int so = 0; so < KS; ++so) rl[so] = BIGF;
        if (ln == 0) {
            if (wv > 0) {
#pragma unroll
                for (int so = 0; so < KS; ++so) rl[so] = ring[wv - 1][(ics + so) & (T - 1)];
            } else if (g == 1) {
#pragma unroll
                for (int so = 0; so < KS; ++so) rl[so] = rlg[so];
            }
        }

        // squared distances for this window (off the dependence chain)
        float Dv[KS];
#pragma unroll
        for (int so = 0; so < KS; ++so) {
            const float d = p[(ics + so) & (T - 1)] - tc;
            Dv[so] = d * d;
        }

        // consumer: issue next chunk's loads now, validate after compute
        f32x4 na, nb4;
        const bool want = consumer && (sb + 1) < NCHUNK;
        const float* basep = eb + (sb + 1) * KS;
        if (want) issue_load8(basep, na, nb4);

        float erow[KS];
#pragma unroll
        for (int so = 0; so < KS; ++so) {
            const int ic = ics + so;
            const float lf = lane_shr1(rl[so], rc);   // left edge (lane0 keeps rl)
            const float t0 = (ic == 0) ? BIGF : top;
            const float cc = (ic == 0) ? zcc : corner;
            const float cell = Dv[so] + softmin3(cc, t0, lf);
            rc = cell; top = cell; corner = lf; result = cell;
            erow[so] = cell;
            if (ln == 63 && wv < WVS - 1 && (unsigned)ic < (unsigned)T)
                ring[wv][ic] = cell;
        }

        // producer: publish completed, 8-aligned chunk (fire-and-forget,
        // NOT drained at the barrier — sentinel validation orders it)
        if (producing && ics >= 0) {
            f32x4 ea = {erow[0], erow[1], erow[2], erow[3]};
            f32x4 eb2 = {erow[4], erow[5], erow[6], erow[7]};
            store_edge8((float*)eb + ics, ea, eb2);
        }

        if (want) {
            await_load8(na, nb4);
            while (has_sent(na, nb4)) {          // rare: lead absorbed jitter
                __builtin_amdgcn_s_sleep(2);
                issue_load8(basep, na, nb4);
                await_load8(na, nb4);
            }
            rlg[0] = na.x; rlg[1] = na.y; rlg[2] = na.z; rlg[3] = na.w;
            rlg[4] = nb4.x; rlg[5] = nb4.y; rlg[6] = nb4.z; rlg[7] = nb4.w;
        }
        block_sync_lds();   // lgkmcnt-only drain: ring ordered, stores fly free
    }

    if (g == G - 1 && tid == NTH - 1) sdtw_out[b] = result;   // cell (1023,1023)
}

// ---------------- fallback: R14-proven single-block kernel (2 cols/thread) ----------------
__global__ __launch_bounds__(512) void sdtw_fb(const float* __restrict__ pred,
                                               const float* __restrict__ targ,
                                               float* __restrict__ sdtw_out) {
    __shared__ float p[T];
    __shared__ float ring[7][T];
    const int b = blockIdx.x;
    const int tid = threadIdx.x;
    const int wv = tid >> 6, ln = tid & 63;
    const int myoff = 71 * wv + ln;
    ((float2*)p)[tid] = ((const float2*)(pred + b * T))[tid];
    const float2 t2v = ((const float2*)(targ + b * T))[tid];
    const float tj0 = t2v.x, tj1 = t2v.y;
    const float zcc = (tid == 0) ? 0.0f : BIGF;
    float top0 = BIGF, top1 = BIGF, corner = BIGF, rc = BIGF, result = 0.0f;
    __syncthreads();
    for (int sb = 0; sb < 198; ++sb) {
        const int ics = sb * 8 - myoff;
        float rl[8];
#pragma unroll
        for (int so = 0; so < 8; ++so) rl[so] = BIGF;
        if (ln == 0 && wv > 0) {
#pragma unroll
            for (int so = 0; so < 8; ++so) rl[so] = ring[wv - 1][(ics + so) & (T - 1)];
        }
        float Dv0[8], Dv1[8];
#pragma unroll
        for (int so = 0; so < 8; ++so) {
            const float pr = p[(ics + so) & (T - 1)];
            const float d0 = pr - tj0, d1 = pr - tj1;
            Dv0[so] = d0 * d0; Dv1[so] = d1 * d1;
        }
#pragma unroll
        for (int so = 0; so < 8; ++so) {
            const int ic = ics + so;
            const float lf = lane_shr1(rl[so], rc);
            const bool r0 = (ic == 0);
            const float t0 = r0 ? BIGF : top0;
            const float t1 = r0 ? BIGF : top1;
            const float cc = r0 ? zcc : corner;
            const float c00 = Dv0[so] + softmin3(cc, t0, lf);
            const float c01 = Dv1[so] + softmin3(t0, t1, c00);
            rc = c01; top0 = c00; top1 = c01; corner = lf; result = c01;
            if (ln == 63 && wv < 7 && (unsigned)ic < (unsigned)T) ring[wv][ic] = c01;
        }
        __syncthreads();
    }
    if (tid == 511) sdtw_out[b] = result;
}

// Single block: QTSE reduction over all B*T elements + combine.
__global__ __launch_bounds__(1024) void finish_kernel(const float* __restrict__ pred,
                                                      const float* __restrict__ targ,
                                                      const float* __restrict__ sdtw,
                                                      float* __restrict__ out) {
    const int tid = threadIdx.x;
    float acc = 0.0f;
    for (int idx = tid; idx < BATCH * T; idx += 1024) {
        const float e = pred[idx] - targ[idx];
        acc += e * e * __expf(KQTSE_ * e);
    }
    for (int off = 32; off; off >>= 1) acc += __shfl_down(acc, off, 64);
    __shared__ float red[16];
    const int wave = tid >> 6, lane = tid & 63;
    if (lane == 0) red[wave] = acc;
    __syncthreads();
    if (tid == 0) {
        float q = 0.0f;
        for (int w = 0; w < 16; ++w) q += red[w];
        q /= (float)(BATCH * T);
        float s = 0.0f;
        for (int bb = 0; bb < BATCH; ++bb) s += sdtw[bb];
        s /= (float)BATCH;
        out[0] = 0.1f * s + 1.0f * q;
    }
}

extern "C" void kernel_launch(void* const* d_in, const int* in_sizes, int n_in,
                              void* d_out, int out_size, void* d_ws, size_t ws_size,
                              hipStream_t stream) {
    const float* pred = (const float*)d_in[0];
    const float* targ = (const float*)d_in[1];
    float* out = (float*)d_out;

    if (ws_size >= WS_NEEDED) {
        float* edges = (float*)d_ws;
        float* sdtw = (float*)((char*)d_ws + SDTW_OFF);
        hipMemsetAsync(d_ws, 0xAA, EDGE_BYTES, stream);   // sentinel-fill edge buffer
        sdtw_pipe<<<BATCH * G, NTH, 0, stream>>>(pred, targ, edges, sdtw);
        finish_kernel<<<1, 1024, 0, stream>>>(pred, targ, sdtw, out);
    } else {
        float* sdtw = (float*)d_ws;   // 32 floats
        sdtw_fb<<<BATCH, 512, 0, stream>>>(pred, targ, sdtw);
        finish_kernel<<<1, 1024, 0, stream>>>(pred, targ, sdtw, out);
    }
}

// Round 16
// 246.850 us; speedup vs baseline: 1.1785x; 1.1785x over previous
//
#include <hip/hip_runtime.h>
#include <hip/hip_bf16.h>

#define BATCH 32
#define T 1024
#define WVS 4                     // 4 waves = 1 wave/SIMD, all 4 SIMDs used
#define CPT 4                     // columns per thread
#define NTH 256                   // 256 threads × 4 cols = 1024
#define KS 8                      // steps per barrier window
#define DOW 75                    // inter-wave offset: >=63+KS, and 3*DOW+63 ≡ 0 (mod 8)
#define SKEW (DOW * (WVS - 1) + 63)   // 288
#define TOT (SKEW + T)            // 1312 (divisible by KS; last thread ends at ic=1023)
#define NB (TOT / KS)             // 164 windows
#define BIGF 1e10f
#define K2f 14.426950408889634f   // 1/(gamma*ln2), gamma=0.1
#define GLN2f 0.0693147180559945f // gamma*ln2
#define KQTSE_ 0.1f

// Raw v_exp_f32 (R14-proven: exp2f's __ocml fixup cost ~40% of the cell).
__device__ __forceinline__ float fexp2(float x) {
    float r;
    asm("v_exp_f32 %0, %1" : "=v"(r) : "v"(x));
    return r;
}

// Exact softmin_gamma(a,b,c): m - g*ln(1 + 2^{K(m-md)} + 2^{K(m-M)}) (one exp folded).
__device__ __forceinline__ float softmin3(float a, float b, float c) {
    float m  = fminf(fminf(a, b), c);             // v_min3_f32
    float M  = fmaxf(fmaxf(a, b), c);             // v_max3_f32
    float md = __builtin_amdgcn_fmed3f(a, b, c);  // v_med3_f32
    float mk = m * K2f;
    float e1 = fexp2(fmaf(-K2f, md, mk));
    float e2 = fexp2(fmaf(-K2f, M, mk));
    return fmaf(-GLN2f, __log2f(1.0f + e1 + e2), m);
}

// lane i gets src[lane i-1]; lane 0 keeps `old` (bound_ctrl=false fuses the select).
__device__ __forceinline__ float lane_shr1(float old, float src) {
    return __int_as_float(__builtin_amdgcn_update_dpp(
        __float_as_int(old), __float_as_int(src), 0x138, 0xF, 0xF, false));
}

// Skewed-wave systolic soft-DTW, 4 waves × 4 cols/thread (geometry-optimized
// R14). One block per batch. Thread (wave w, lane l) owns cols [4*tid,4*tid+4),
// processes row ic at step s = ic + 75*w + l. Per-SIMD issue per window equals
// R14's (32 cells), but SKEW shrinks 560->288 (164 windows vs 198) and the
// barrier covers 4 waves instead of 8. Chain at 1 wave/SIMD = DPP + 4 serial
// softmins ~225 cy < issue ~264 cy/step -> still issue-bound (R9's trap was
// bpermute's ~300cy chain; DPP keeps it under). Left edge via DPP wave-shift;
// wave boundary via LDS ring + 1 barrier per KS=8 steps (lag DOW-63=12>=KS
// keeps the ordering proof). No guards on compute: garbage cells provably
// never reach an in-range consumer (consumer-in-range => producer-in-range;
// ic==0 selects reset state; ring writes ARE guarded).
__global__ __launch_bounds__(NTH) void sdtw_kernel(const float* __restrict__ pred,
                                                   const float* __restrict__ targ,
                                                   float* __restrict__ sdtw_out) {
    __shared__ float p[T];
    __shared__ float ring[WVS - 1][T];   // 12 KB

    const int b = blockIdx.x;
    const int tid = threadIdx.x;
    const int wv = tid >> 6;
    const int ln = tid & 63;
    const int myoff = DOW * wv + ln;

    ((float4*)p)[tid] = ((const float4*)(pred + b * T))[tid];
    const float4 t4 = ((const float4*)(targ + b * T))[tid];
    const float tj0 = t4.x, tj1 = t4.y, tj2 = t4.z, tj3 = t4.w;
    const float zcc = (tid == 0) ? 0.0f : BIGF;   // R[0][0]=0, else boundary BIG

    float top0 = BIGF, top1 = BIGF, top2 = BIGF, top3 = BIGF;  // previous row
    float corner = BIGF;              // cell (ic-1, 4*tid-1) (diag)
    float rc = BIGF;                  // my previous step's rightmost cell
    float result = 0.0f;

    __syncthreads();

    for (int sb = 0; sb < NB; ++sb) {
        const int ics = sb * KS - myoff;

        // lane-0 left-edge batch for waves 1..3 (off the dependence chain)
        float rl[KS];
#pragma unroll
        for (int so = 0; so < KS; ++so) rl[so] = BIGF;
        if (ln == 0 && wv > 0) {
#pragma unroll
            for (int so = 0; so < KS; ++so) rl[so] = ring[wv - 1][(ics + so) & (T - 1)];
        }

        // squared distances for this window (off the dependence chain)
        float Dv0[KS], Dv1[KS], Dv2[KS], Dv3[KS];
#pragma unroll
        for (int so = 0; so < KS; ++so) {
            const float pr = p[(ics + so) & (T - 1)];
            const float d0 = pr - tj0, d1 = pr - tj1, d2 = pr - tj2, d3 = pr - tj3;
            Dv0[so] = d0 * d0; Dv1[so] = d1 * d1; Dv2[so] = d2 * d2; Dv3[so] = d3 * d3;
        }

#pragma unroll
        for (int so = 0; so < KS; ++so) {
            const int ic = ics + so;
            // left edge: lane l-1's previous-step rightmost cell; lane 0 keeps rl[so]
            const float lf = lane_shr1(rl[so], rc);
            const bool r0 = (ic == 0);
            const float t0 = r0 ? BIGF : top0;
            const float t1 = r0 ? BIGF : top1;
            const float t2 = r0 ? BIGF : top2;
            const float t3 = r0 ? BIGF : top3;
            const float cc = r0 ? zcc : corner;

            const float c0 = Dv0[so] + softmin3(cc, t0, lf);
            const float c1 = Dv1[so] + softmin3(t0, t1, c0);
            const float c2 = Dv2[so] + softmin3(t1, t2, c1);
            const float c3 = Dv3[so] + softmin3(t2, t3, c2);

            rc = c3; top0 = c0; top1 = c1; top2 = c2; top3 = c3;
            corner = lf; result = c3;
            if (ln == 63 && wv < WVS - 1 && (unsigned)ic < (unsigned)T)
                ring[wv][ic] = c3;
        }
        __syncthreads();   // publishes this window's ring writes for the next window
    }

    if (tid == NTH - 1) sdtw_out[b] = result;   // cell (1023,1023)
}

// Single block: QTSE reduction over all B*T elements + combine.
__global__ __launch_bounds__(1024) void finish_kernel(const float* __restrict__ pred,
                                                      const float* __restrict__ targ,
                                                      const float* __restrict__ sdtw,
                                                      float* __restrict__ out) {
    const int tid = threadIdx.x;
    float acc = 0.0f;
    for (int idx = tid; idx < BATCH * T; idx += 1024) {
        const float e = pred[idx] - targ[idx];
        acc += e * e * __expf(KQTSE_ * e);
    }
    for (int off = 32; off; off >>= 1) acc += __shfl_down(acc, off, 64);
    __shared__ float red[16];
    const int wave = tid >> 6, lane = tid & 63;
    if (lane == 0) red[wave] = acc;
    __syncthreads();
    if (tid == 0) {
        float q = 0.0f;
        for (int w = 0; w < 16; ++w) q += red[w];
        q /= (float)(BATCH * T);
        float s = 0.0f;
        for (int bb = 0; bb < BATCH; ++bb) s += sdtw[bb];
        s /= (float)BATCH;
        out[0] = 0.1f * s + 1.0f * q;
    }
}

extern "C" void kernel_launch(void* const* d_in, const int* in_sizes, int n_in,
                              void* d_out, int out_size, void* d_ws, size_t ws_size,
                              hipStream_t stream) {
    const float* pred = (const float*)d_in[0];
    const float* targ = (const float*)d_in[1];
    float* out = (float*)d_out;
    float* sdtw = (float*)d_ws;   // 32 floats of scratch

    sdtw_kernel<<<BATCH, NTH, 0, stream>>>(pred, targ, sdtw);
    finish_kernel<<<1, 1024, 0, stream>>>(pred, targ, sdtw, out);
}

// Round 17
// 244.052 us; speedup vs baseline: 1.1920x; 1.0115x over previous
//
#include <hip/hip_runtime.h>
#include <hip/hip_bf16.h>

#define BATCH 32
#define T 1024
#define WVS 4                     // 4 waves = 1 wave/SIMD, all 4 SIMDs used
#define CPT 4                     // columns per thread
#define NTH 256                   // 256 threads × 4 cols = 1024
#define KS 16                     // steps per barrier window (R17: 8->16, amortize O)
#define DOW 79                    // inter-wave offset: >= 63 + KS (lag = 16 = KS)
#define SKEW (DOW * (WVS - 1) + 63)   // 300
#define TOT (SKEW + T)            // 1324
#define NB ((TOT + KS - 1) / KS)  // 83 windows (covers 1328 steps; 4-step overhang)
#define BIGF 1e10f
#define K2f 14.426950408889634f   // 1/(gamma*ln2), gamma=0.1
#define GLN2f 0.0693147180559945f // gamma*ln2
#define KQTSE_ 0.1f

// Raw v_exp_f32 (R14-proven: exp2f's __ocml fixup cost ~40% of the cell).
__device__ __forceinline__ float fexp2(float x) {
    float r;
    asm("v_exp_f32 %0, %1" : "=v"(r) : "v"(x));
    return r;
}

// Exact softmin_gamma(a,b,c): m - g*ln(1 + 2^{K(m-md)} + 2^{K(m-M)}) (one exp folded).
__device__ __forceinline__ float softmin3(float a, float b, float c) {
    float m  = fminf(fminf(a, b), c);             // v_min3_f32
    float M  = fmaxf(fmaxf(a, b), c);             // v_max3_f32
    float md = __builtin_amdgcn_fmed3f(a, b, c);  // v_med3_f32
    float mk = m * K2f;
    float e1 = fexp2(fmaf(-K2f, md, mk));
    float e2 = fexp2(fmaf(-K2f, M, mk));
    return fmaf(-GLN2f, __log2f(1.0f + e1 + e2), m);
}

// lane i gets src[lane i-1]; lane 0 keeps `old` (bound_ctrl=false fuses the select).
__device__ __forceinline__ float lane_shr1(float old, float src) {
    return __int_as_float(__builtin_amdgcn_update_dpp(
        __float_as_int(old), __float_as_int(src), 0x138, 0xF, 0xF, false));
}

// Skewed-wave systolic soft-DTW, 4 waves × 4 cols/thread, KS=16.
// One block per batch. Thread (wave w, lane l) owns cols [4*tid,4*tid+4),
// processes row ic at step s = ic + 79*w + l. R16 proved per-window overhead
// O ~ 1370 cy is the residual cost at 1 wave/SIMD (prologue ds_read latency +
// barrier, exposed with no co-wave); KS=16 halves the window count (164->83)
// to amortize it. Ordering proof: lag = DOW-63 = 16 = KS => every ring write
// lands >= 1 full window before its read. The 4-step overhang (NB*KS=1328 >
// TOT=1324) requires masking the `result` update by ic<T (tid 255 computes
// garbage ic>=1024 in the final window). All other garbage-cell reachability
// arguments identical to the R16-proven kernel (ring writes guarded;
// beyond-range producers only feed beyond-range consumers).
__global__ __launch_bounds__(NTH) void sdtw_kernel(const float* __restrict__ pred,
                                                   const float* __restrict__ targ,
                                                   float* __restrict__ sdtw_out) {
    __shared__ float p[T];
    __shared__ float ring[WVS - 1][T];   // 12 KB

    const int b = blockIdx.x;
    const int tid = threadIdx.x;
    const int wv = tid >> 6;
    const int ln = tid & 63;
    const int myoff = DOW * wv + ln;

    ((float4*)p)[tid] = ((const float4*)(pred + b * T))[tid];
    const float4 t4 = ((const float4*)(targ + b * T))[tid];
    const float tj0 = t4.x, tj1 = t4.y, tj2 = t4.z, tj3 = t4.w;
    const float zcc = (tid == 0) ? 0.0f : BIGF;   // R[0][0]=0, else boundary BIG

    float top0 = BIGF, top1 = BIGF, top2 = BIGF, top3 = BIGF;  // previous row
    float corner = BIGF;              // cell (ic-1, 4*tid-1) (diag)
    float rc = BIGF;                  // my previous step's rightmost cell
    float result = 0.0f;

    __syncthreads();

    for (int sb = 0; sb < NB; ++sb) {
        const int ics = sb * KS - myoff;

        // lane-0 left-edge batch for waves 1..3 (off the dependence chain)
        float rl[KS];
#pragma unroll
        for (int so = 0; so < KS; ++so) rl[so] = BIGF;
        if (ln == 0 && wv > 0) {
#pragma unroll
            for (int so = 0; so < KS; ++so) rl[so] = ring[wv - 1][(ics + so) & (T - 1)];
        }

        // squared distances for this window (off the dependence chain)
        float Dv0[KS], Dv1[KS], Dv2[KS], Dv3[KS];
#pragma unroll
        for (int so = 0; so < KS; ++so) {
            const float pr = p[(ics + so) & (T - 1)];
            const float d0 = pr - tj0, d1 = pr - tj1, d2 = pr - tj2, d3 = pr - tj3;
            Dv0[so] = d0 * d0; Dv1[so] = d1 * d1; Dv2[so] = d2 * d2; Dv3[so] = d3 * d3;
        }

#pragma unroll
        for (int so = 0; so < KS; ++so) {
            const int ic = ics + so;
            // left edge: lane l-1's previous-step rightmost cell; lane 0 keeps rl[so]
            const float lf = lane_shr1(rl[so], rc);
            const bool r0 = (ic == 0);
            const float t0 = r0 ? BIGF : top0;
            const float t1 = r0 ? BIGF : top1;
            const float t2 = r0 ? BIGF : top2;
            const float t3 = r0 ? BIGF : top3;
            const float cc = r0 ? zcc : corner;

            const float c0 = Dv0[so] + softmin3(cc, t0, lf);
            const float c1 = Dv1[so] + softmin3(t0, t1, c0);
            const float c2 = Dv2[so] + softmin3(t1, t2, c1);
            const float c3 = Dv3[so] + softmin3(t2, t3, c2);

            rc = c3; top0 = c0; top1 = c1; top2 = c2; top3 = c3;
            corner = lf;
            if ((unsigned)ic < (unsigned)T) result = c3;   // mask overhang garbage
            if (ln == 63 && wv < WVS - 1 && (unsigned)ic < (unsigned)T)
                ring[wv][ic] = c3;
        }
        __syncthreads();   // publishes this window's ring writes for the next window
    }

    if (tid == NTH - 1) sdtw_out[b] = result;   // cell (1023,1023)
}

// Single block: QTSE reduction over all B*T elements + combine.
__global__ __launch_bounds__(1024) void finish_kernel(const float* __restrict__ pred,
                                                      const float* __restrict__ targ,
                                                      const float* __restrict__ sdtw,
                                                      float* __restrict__ out) {
    const int tid = threadIdx.x;
    float acc = 0.0f;
    for (int idx = tid; idx < BATCH * T; idx += 1024) {
        const float e = pred[idx] - targ[idx];
        acc += e * e * __expf(KQTSE_ * e);
    }
    for (int off = 32; off; off >>= 1) acc += __shfl_down(acc, off, 64);
    __shared__ float red[16];
    const int wave = tid >> 6, lane = tid & 63;
    if (lane == 0) red[wave] = acc;
    __syncthreads();
    if (tid == 0) {
        float q = 0.0f;
        for (int w = 0; w < 16; ++w) q += red[w];
        q /= (float)(BATCH * T);
        float s = 0.0f;
        for (int bb = 0; bb < BATCH; ++bb) s += sdtw[bb];
        s /= (float)BATCH;
        out[0] = 0.1f * s + 1.0f * q;
    }
}

extern "C" void kernel_launch(void* const* d_in, const int* in_sizes, int n_in,
                              void* d_out, int out_size, void* d_ws, size_t ws_size,
                              hipStream_t stream) {
    const float* pred = (const float*)d_in[0];
    const float* targ = (const float*)d_in[1];
    float* out = (float*)d_out;
    float* sdtw = (float*)d_ws;   // 32 floats of scratch

    sdtw_kernel<<<BATCH, NTH, 0, stream>>>(pred, targ, sdtw);
    finish_kernel<<<1, 1024, 0, stream>>>(pred, targ, sdtw, out);
}